// Round 6
// baseline (206.507 us; speedup 1.0000x reference)
//
#include <hip/hip_runtime.h>
#include <hip/hip_bf16.h>
#include <stdint.h>

typedef __attribute__((ext_vector_type(8))) short short8;
typedef __attribute__((ext_vector_type(4))) float f32x4;

union FragU { short8 s; __hip_bfloat162 h[4]; };

__device__ __forceinline__ unsigned short f2bf(float f) {
  union { float f; unsigned int u; } v; v.f = f;
  unsigned int r = v.u + 0x7fffu + ((v.u >> 16) & 1u);
  return (unsigned short)(r >> 16);
}

// async global -> LDS, 16B per lane. LDS dest = uniform base + lane*16 (linear).
#define GLOAD_LDS16(gp, lp) \
  __builtin_amdgcn_global_load_lds((const __attribute__((address_space(1))) void*)(gp), \
                                   (__attribute__((address_space(3))) void*)(lp), 16, 0, 0)

// ---------------------------------------------------------------------------
// Kernel 0: bT[e][k] = bf16( (rel @ GW)[k][e] )   (64 x 4096); zero accums.
// grid 64 x 256
// ---------------------------------------------------------------------------
__global__ void k_prep(const float* __restrict__ rel, const float* __restrict__ GW,
                       unsigned short* __restrict__ bT, float* __restrict__ accums) {
  __shared__ float tile[64][65];   // rel rows j*64..+64  [k][i]
  __shared__ float gws[64][64];    // GW [i][e]
  const int j = blockIdx.x;
  const int t = threadIdx.x;
#pragma unroll
  for (int p = 0; p < 16; ++p) {
    int elem = p * 256 + t;
    int kk = elem >> 6, ee = elem & 63;
    tile[kk][ee] = rel[(j * 64 + kk) * 64 + ee];
    ((float*)gws)[elem] = GW[elem];
  }
  __syncthreads();
  const int e = t >> 2, chunk = t & 3;
  union { unsigned short u16[16]; uint4 v[2]; } tmp;
  for (int i = 0; i < 16; ++i) {
    float acc = 0.f;
#pragma unroll
    for (int ii = 0; ii < 64; ++ii) acc += tile[chunk * 16 + i][ii] * gws[ii][e];
    tmp.u16[i] = f2bf(acc);
  }
  unsigned short* dst = bT + e * 4096 + j * 64 + chunk * 16;
  *(uint4*)(dst) = tmp.v[0];
  *(uint4*)(dst + 8) = tmp.v[1];
  if (j == 0) {
    accums[t] = 0.f; accums[t + 256] = 0.f; accums[t + 512] = 0.f; accums[t + 768] = 0.f;
  }
}

// ---------------------------------------------------------------------------
// Fused main kernel.
//   blocks 0..511   : GEMM  C = link[b][64 rows] @ relGW  (K=4096, cols=64)
//     per 128-k step: A (64x128 fp32, 32 KB) staged via global_load_lds with
//     contiguous 1KB-per-instr reads (2 rows/instr) and source-side XOR
//     swizzle; B (64x128 bf16, 16 KB) staged same way from L2-hot bT.
//     Compute: 4 k-chunks of 32 -> 4 MFMAs per nt per step.
//     Epilogue: relu(C + bias) column-sum -> atomicAdd pooled_sum.
//   blocks 512..527 : tree attention (4 trees per block, one per wave)
// ---------------------------------------------------------------------------
__global__ __launch_bounds__(256, 3) void k_main(
    const float* __restrict__ link, const unsigned short* __restrict__ bT,
    const float* __restrict__ gbias, float* __restrict__ pooled_sum,
    const float* __restrict__ col_table, const float* __restrict__ rel_table,
    const float* __restrict__ Wk, const float* __restrict__ Wq, const float* __restrict__ Wv,
    const int* __restrict__ table_ids, const int* __restrict__ l_ids,
    const int* __restrict__ r_ids, float* __restrict__ tree_emb) {
  __shared__ union {
    struct { char a[64 * 512]; char b[64 * 256]; } g;          // 48 KB
    struct { float W3[3][64][64]; float qT[4][64][4]; } tr;    // 52 KB
  } sm;

  const int t = threadIdx.x;
  const int lane = t & 63;
  const int wid = t >> 6;

  if (blockIdx.x < 512) {
    // ------------------------ GEMM branch ------------------------
    const int b = blockIdx.x >> 6;
    const int rowBase = (blockIdx.x & 63) * 64;
    const int wrow = wid * 16;
    const int g = lane >> 4;          // k-group 0..3
    const int r = lane & 15;          // row/col within fragment
    const uint32_t fr = (uint32_t)((r & 7) << 4);

    const char* linkb = (const char*)(link + ((size_t)b << 24));
    // A staging: instr i covers rows (wrow+i*2, wrow+i*2+1); lane l reads
    // 16B at within-row byte ((l&31)*16) ^ ((row&7)<<4), row = +(l>>5).
    const int s_arow = wrow + (lane >> 5);               // + i*2
    const uint32_t s_acb = (uint32_t)((lane & 31) * 16);
    // B staging: instr i covers e-rows (wid*16+i*4 .. +3); lane l: e += l>>4.
    const int s_brow = wid * 16 + (lane >> 4);           // + i*4
    const uint32_t s_bcb = (uint32_t)((lane & 15) * 16);

    f32x4 acc[4];
#pragma unroll
    for (int nt = 0; nt < 4; ++nt) acc[nt] = (f32x4){0.f, 0.f, 0.f, 0.f};

    for (int k0 = 0; k0 < 4096; k0 += 128) {
      // ---- stage A: 8 instrs/wave, 1KB contiguous (2 rows) each ----
#pragma unroll
      for (int i = 0; i < 8; ++i) {
        const int row = s_arow + i * 2;
        const uint32_t cb = s_acb ^ ((uint32_t)(row & 7) << 4);
        GLOAD_LDS16(linkb + ((size_t)(rowBase + row) * 4096 + (size_t)k0) * 4 + cb,
                    sm.g.a + (wrow + i * 2) * 512);
      }
      // ---- stage B: 4 instrs/wave from bT (L2-hot) ----
#pragma unroll
      for (int i = 0; i < 4; ++i) {
        const int e = s_brow + i * 4;
        const uint32_t cb = s_bcb ^ ((uint32_t)(e & 7) << 4);
        GLOAD_LDS16((const char*)bT + (size_t)e * 8192 + (size_t)k0 * 2 + cb,
                    sm.g.b + (wid * 16 + i * 4) * 256);
      }
      __syncthreads();

      const char* abase = sm.g.a + (wrow + r) * 512;
#pragma unroll
      for (int kc = 0; kc < 4; ++kc) {
        const uint32_t o0 = ((uint32_t)(kc * 128 + g * 32)) ^ fr;
        const f32x4 a0 = *(const f32x4*)(abase + o0);
        const f32x4 a1 = *(const f32x4*)(abase + (o0 ^ 16));
        FragU f;
        f.h[0] = __float22bfloat162_rn(float2{a0[0], a0[1]});
        f.h[1] = __float22bfloat162_rn(float2{a0[2], a0[3]});
        f.h[2] = __float22bfloat162_rn(float2{a1[0], a1[1]});
        f.h[3] = __float22bfloat162_rn(float2{a1[2], a1[3]});
        const uint32_t ob = ((uint32_t)(kc * 64 + g * 16)) ^ fr;
#pragma unroll
        for (int nt = 0; nt < 4; ++nt) {
          const short8 bf = *(const short8*)(sm.g.b + (nt * 16 + r) * 256 + ob);
          acc[nt] = __builtin_amdgcn_mfma_f32_16x16x32_bf16(f.s, bf, acc[nt], 0, 0, 0);
        }
      }
      __syncthreads();
    }

    // ---- epilogue: relu(C + bias) colsum, all in registers ----
    float part[4];
#pragma unroll
    for (int nt = 0; nt < 4; ++nt) {
      const float gbv = gbias[nt * 16 + r];
      float s = 0.f;
#pragma unroll
      for (int j = 0; j < 4; ++j) s += fmaxf(acc[nt][j] + gbv, 0.f);
      s += __shfl_xor(s, 16);
      s += __shfl_xor(s, 32);
      part[nt] = s;
    }
    float* pr = (float*)sm.g.a;   // safe: k-loop ended with __syncthreads
    if (g == 0) {
#pragma unroll
      for (int nt = 0; nt < 4; ++nt) pr[(wid * 4 + nt) * 16 + r] = part[nt];
    }
    __syncthreads();
    if (t < 64) {
      const int nt = t >> 4, c16 = t & 15;
      float s = pr[(0 + nt) * 16 + c16] + pr[(4 + nt) * 16 + c16] +
                pr[(8 + nt) * 16 + c16] + pr[(12 + nt) * 16 + c16];
      atomicAdd(&pooled_sum[b * 64 + t], s);
    }
  } else {
    // ------------------------- tree branch -------------------------
    const int e = lane;
    for (int i = t; i < 4096; i += 256) {
      ((float*)sm.tr.W3[0])[i] = Wk[i];
      ((float*)sm.tr.W3[1])[i] = Wq[i];
      ((float*)sm.tr.W3[2])[i] = Wv[i];
    }
    __syncthreads();

    const int tree = (blockIdx.x - 512) * 4 + wid;   // 0..63
    const int b = tree >> 3;
    const int* tid = table_ids + tree * 17;
    const int* lid = l_ids + tree * 32;
    const int* rid = r_ids + tree * 32;

    float prev = rel_table[tid[0] * 64 + e];

    for (int d = 0; d < 16; ++d) {
      const int l0 = lid[d * 2], l1 = lid[d * 2 + 1];
      const int r0 = rid[d * 2], r1 = rid[d * 2 + 1];
      const float lce = 0.5f * (col_table[l0 * 64 + e] + col_table[l1 * 64 + e]);
      const float rce = 0.5f * (col_table[r0 * 64 + e] + col_table[r1 * 64 + e]);
      const float rte = rel_table[tid[1 + d] * 64 + e];
      float4 qv0; qv0.x = prev; qv0.y = lce; qv0.z = rce; qv0.w = rte;
      *(float4*)&sm.tr.qT[wid][e][0] = qv0;
      __syncthreads();

      float K[4] = {0, 0, 0, 0}, Q[4] = {0, 0, 0, 0}, V[4] = {0, 0, 0, 0};
#pragma unroll 8
      for (int i = 0; i < 64; ++i) {
        const f32x4 qv = *(const f32x4*)&sm.tr.qT[wid][i][0];
        const float wk = sm.tr.W3[0][i][e];
        const float wq = sm.tr.W3[1][i][e];
        const float wvv = sm.tr.W3[2][i][e];
#pragma unroll
        for (int j = 0; j < 4; ++j) {
          K[j] += qv[j] * wk;
          Q[j] += qv[j] * wq;
          V[j] += qv[j] * wvv;
        }
      }

      float sc[4][4];
#pragma unroll
      for (int j = 0; j < 4; ++j)
#pragma unroll
        for (int k = 0; k < 4; ++k) {
          float p = Q[j] * K[k];
          p += __shfl_xor(p, 1);  p += __shfl_xor(p, 2);  p += __shfl_xor(p, 4);
          p += __shfl_xor(p, 8);  p += __shfl_xor(p, 16); p += __shfl_xor(p, 32);
          sc[j][k] = p * (1.f / 64.f);
        }

      float wsum[4] = {0, 0, 0, 0};
#pragma unroll
      for (int j = 0; j < 4; ++j) {
        float mx = fmaxf(fmaxf(sc[j][0], sc[j][1]), fmaxf(sc[j][2], sc[j][3]));
        float a0 = __expf(sc[j][0] - mx), a1 = __expf(sc[j][1] - mx);
        float a2 = __expf(sc[j][2] - mx), a3 = __expf(sc[j][3] - mx);
        float inv = 1.f / (a0 + a1 + a2 + a3);
        wsum[0] += a0 * inv; wsum[1] += a1 * inv; wsum[2] += a2 * inv; wsum[3] += a3 * inv;
      }

      prev = wsum[0] * V[0] + wsum[1] * V[1] + wsum[2] * V[2] + wsum[3] * V[3];
      __syncthreads();
    }
    atomicAdd(&tree_emb[b * 64 + e], prev);
  }
}

// ---------------------------------------------------------------------------
// Kernel 2: logits = [pooled_sum/4096 || tree_emb] @ fc_w  + clip(log(mask))
// grid 128 x 256
// ---------------------------------------------------------------------------
__global__ void k_final(const float* __restrict__ action_mask, const float* __restrict__ fc_w,
                        const float* __restrict__ pooled_sum, const float* __restrict__ tree_emb,
                        float* __restrict__ out) {
  __shared__ float c[128];
  const int b = blockIdx.x >> 4;
  const int a = ((blockIdx.x & 15) << 8) + threadIdx.x;
  if (threadIdx.x < 128) {
    c[threadIdx.x] = (threadIdx.x < 64) ? pooled_sum[b * 64 + threadIdx.x] * (1.f / 4096.f)
                                        : tree_emb[b * 64 + threadIdx.x - 64];
  }
  __syncthreads();
  float acc = 0.f;
  for (int i = 0; i < 128; ++i) acc += c[i] * fc_w[i * 4096 + a];
  const float m = action_mask[b * 4096 + a];
  float lg = __logf(m);
  lg = fminf(fmaxf(lg, -3.4e38f), 3.4e38f);
  out[b * 4096 + a] = lg + acc;
}

// ---------------------------------------------------------------------------
extern "C" void kernel_launch(void* const* d_in, const int* in_sizes, int n_in,
                              void* d_out, int out_size, void* d_ws, size_t ws_size,
                              hipStream_t stream) {
  const float* link = (const float*)d_in[0];
  const float* mask = (const float*)d_in[1];
  const float* col = (const float*)d_in[2];
  const float* rel = (const float*)d_in[3];
  const float* GW = (const float*)d_in[4];
  const float* gb = (const float*)d_in[5];
  const float* Wk = (const float*)d_in[6];
  const float* Wq = (const float*)d_in[7];
  const float* Wv = (const float*)d_in[8];
  const float* fcw = (const float*)d_in[9];
  const int* tids = (const int*)d_in[10];
  const int* lids = (const int*)d_in[11];
  const int* rids = (const int*)d_in[12];
  float* out = (float*)d_out;

  unsigned short* bT = (unsigned short*)d_ws;               // 512 KB  (relGW^T bf16)
  float* accums = (float*)((char*)d_ws + 512 * 1024);       // 1024 floats
  float* pooled_sum = accums;                               // [8][64]
  float* tree = accums + 512;                               // [8][64]

  hipLaunchKernelGGL(k_prep, dim3(64), dim3(256), 0, stream, rel, GW, bT, accums);
  hipLaunchKernelGGL(k_main, dim3(528), dim3(256), 0, stream,
                     link, bT, gb, pooled_sum,
                     col, rel, Wk, Wq, Wv, tids, lids, rids, tree);
  hipLaunchKernelGGL(k_final, dim3(128), dim3(256), 0, stream, mask, fcw, pooled_sum, tree, out);
}

// Round 7
// 200.896 us; speedup vs baseline: 1.0279x; 1.0279x over previous
//
#include <hip/hip_runtime.h>
#include <hip/hip_bf16.h>
#include <stdint.h>

typedef __attribute__((ext_vector_type(8))) short short8;
typedef __attribute__((ext_vector_type(4))) float f32x4;

union FragU { short8 s; __hip_bfloat162 h[4]; };

__device__ __forceinline__ unsigned short f2bf(float f) {
  union { float f; unsigned int u; } v; v.f = f;
  unsigned int r = v.u + 0x7fffu + ((v.u >> 16) & 1u);
  return (unsigned short)(r >> 16);
}

// async global -> LDS, 16B per lane. LDS dest = uniform base + lane*16 (linear).
#define GLOAD_LDS16(gp, lp) \
  __builtin_amdgcn_global_load_lds((const __attribute__((address_space(1))) void*)(gp), \
                                   (__attribute__((address_space(3))) void*)(lp), 16, 0, 0)

// ---------------------------------------------------------------------------
// Kernel 0: bT[e][k] = bf16( (rel @ GW)[k][e] )   (64 x 4096); zero accums.
// grid 64 x 256
// ---------------------------------------------------------------------------
__global__ void k_prep(const float* __restrict__ rel, const float* __restrict__ GW,
                       unsigned short* __restrict__ bT, float* __restrict__ accums) {
  __shared__ float tile[64][65];   // rel rows j*64..+64  [k][i]
  __shared__ float gws[64][64];    // GW [i][e]
  const int j = blockIdx.x;
  const int t = threadIdx.x;
#pragma unroll
  for (int p = 0; p < 16; ++p) {
    int elem = p * 256 + t;
    int kk = elem >> 6, ee = elem & 63;
    tile[kk][ee] = rel[(j * 64 + kk) * 64 + ee];
    ((float*)gws)[elem] = GW[elem];
  }
  __syncthreads();
  const int e = t >> 2, chunk = t & 3;
  union { unsigned short u16[16]; uint4 v[2]; } tmp;
  for (int i = 0; i < 16; ++i) {
    float acc = 0.f;
#pragma unroll
    for (int ii = 0; ii < 64; ++ii) acc += tile[chunk * 16 + i][ii] * gws[ii][e];
    tmp.u16[i] = f2bf(acc);
  }
  unsigned short* dst = bT + e * 4096 + j * 64 + chunk * 16;
  *(uint4*)(dst) = tmp.v[0];
  *(uint4*)(dst + 8) = tmp.v[1];
  if (j == 0) {
    accums[t] = 0.f; accums[t + 256] = 0.f; accums[t + 512] = 0.f; accums[t + 768] = 0.f;
  }
}

// ---------------------------------------------------------------------------
// Fused main kernel.
//   blocks 0..511   : GEMM  C = link[b][64 rows] @ relGW  (K=4096, cols=64)
//     T3-minimal 2-phase: double-buffered 64x64 tiles; stage tile t+1 via
//     global_load_lds BEFORE computing tile t; ONE drain+barrier per tile so
//     the next tile's 24 KB stays in flight during all compute.
//   blocks 512..527 : tree attention (4 trees per block, one per wave)
// ---------------------------------------------------------------------------
__global__ __launch_bounds__(256, 3) void k_main(
    const float* __restrict__ link, const unsigned short* __restrict__ bT,
    const float* __restrict__ gbias, float* __restrict__ pooled_sum,
    const float* __restrict__ col_table, const float* __restrict__ rel_table,
    const float* __restrict__ Wk, const float* __restrict__ Wq, const float* __restrict__ Wv,
    const int* __restrict__ table_ids, const int* __restrict__ l_ids,
    const int* __restrict__ r_ids, float* __restrict__ tree_emb) {
  __shared__ union {
    struct { char a[2][64 * 256]; char b[2][64 * 128]; } g;    // 48 KB
    struct { float W3[3][64][64]; float qT[4][64][4]; } tr;    // 52 KB
  } sm;

  const int t = threadIdx.x;
  const int lane = t & 63;
  const int wid = t >> 6;

  if (blockIdx.x < 512) {
    // ------------------------ GEMM branch ------------------------
    const int b = blockIdx.x >> 6;
    const int rowBase = (blockIdx.x & 63) * 64;
    const int wrow = wid * 16;
    const int g = lane >> 4;          // k-group 0..3
    const int r = lane & 15;          // row/col within fragment
    const uint32_t fr = (uint32_t)((r & 7) << 4);

    const char* linkb = (const char*)(link + ((size_t)b << 24));
    // A stage: 4 instrs/wave, each 1KB = 4 rows x 256B.
    //   lane l: row = wrow + 4j + (l>>4), src byte ((l&15)*16) ^ ((row&7)<<4)
    const int a_ri = lane >> 4;                    // row within instr
    const uint32_t a_cb = (uint32_t)((lane & 15) * 16);
    // B stage: 2 instrs/wave, each 1KB = 8 e-rows x 128B.
    //   lane l: e = wrow + 8j + (l>>3), src byte ((l&7)*16) ^ ((e&7)<<4)
    const int b_ei = lane >> 3;                    // e within instr (0..7)
    const uint32_t b_cb = (uint32_t)(((lane & 7) * 16) ^ ((uint32_t)(lane >> 3) << 4));

    f32x4 acc[4];
#pragma unroll
    for (int nt = 0; nt < 4; ++nt) acc[nt] = (f32x4){0.f, 0.f, 0.f, 0.f};

#define STAGE(buf, tt) do {                                                     \
    const size_t ka = (size_t)(tt) * 256;  /* 64k * 4B */                       \
    _Pragma("unroll")                                                           \
    for (int j = 0; j < 4; ++j) {                                               \
      const int row = wrow + 4 * j + a_ri;                                      \
      const uint32_t cb = a_cb ^ ((uint32_t)(row & 7) << 4);                    \
      GLOAD_LDS16(linkb + (size_t)(rowBase + row) * 16384 + ka + cb,            \
                  sm.g.a[buf] + (wrow + 4 * j) * 256);                          \
    }                                                                           \
    const size_t kb = (size_t)(tt) * 128;  /* 64k * 2B */                       \
    _Pragma("unroll")                                                           \
    for (int j = 0; j < 2; ++j) {                                               \
      const int e = wrow + 8 * j + b_ei;                                        \
      GLOAD_LDS16((const char*)bT + (size_t)e * 8192 + kb + b_cb,               \
                  sm.g.b[buf] + (wrow + 8 * j) * 128);                          \
    }                                                                           \
  } while (0)

#define COMPUTE(buf) do {                                                       \
    const char* ab = sm.g.a[buf] + (wrow + r) * 256;                            \
    const char* bb = sm.g.b[buf];                                               \
    _Pragma("unroll")                                                           \
    for (int kc = 0; kc < 2; ++kc) {                                            \
      const uint32_t o0 = ((uint32_t)(kc * 128 + g * 32)) ^ fr;                 \
      const f32x4 a0 = *(const f32x4*)(ab + o0);                                \
      const f32x4 a1 = *(const f32x4*)(ab + (o0 ^ 16));                         \
      FragU f;                                                                  \
      f.h[0] = __float22bfloat162_rn(float2{a0[0], a0[1]});                     \
      f.h[1] = __float22bfloat162_rn(float2{a0[2], a0[3]});                     \
      f.h[2] = __float22bfloat162_rn(float2{a1[0], a1[1]});                     \
      f.h[3] = __float22bfloat162_rn(float2{a1[2], a1[3]});                     \
      const uint32_t ob = ((uint32_t)(kc * 64 + g * 16)) ^ fr;                  \
      _Pragma("unroll")                                                         \
      for (int nt = 0; nt < 4; ++nt) {                                          \
        const short8 bf = *(const short8*)(bb + (nt * 16 + r) * 128 + ob);      \
        acc[nt] = __builtin_amdgcn_mfma_f32_16x16x32_bf16(f.s, bf, acc[nt], 0, 0, 0); \
      }                                                                         \
    }                                                                           \
  } while (0)

    STAGE(0, 0);
    __syncthreads();
    int cur = 0;
    for (int tt = 0; tt < 64; ++tt) {
      if (tt < 63) STAGE(cur ^ 1, tt + 1);   // in flight during compute
      COMPUTE(cur);
      __syncthreads();                        // drains vmcnt; next buf ready
      cur ^= 1;
    }

    // ---- epilogue: relu(C + bias) colsum, all in registers ----
    float part[4];
#pragma unroll
    for (int nt = 0; nt < 4; ++nt) {
      const float gbv = gbias[nt * 16 + r];
      float s = 0.f;
#pragma unroll
      for (int j = 0; j < 4; ++j) s += fmaxf(acc[nt][j] + gbv, 0.f);
      s += __shfl_xor(s, 16);
      s += __shfl_xor(s, 32);
      part[nt] = s;
    }
    float* pr = (float*)sm.g.a[0];
    if (g == 0) {
#pragma unroll
      for (int nt = 0; nt < 4; ++nt) pr[(wid * 4 + nt) * 16 + r] = part[nt];
    }
    __syncthreads();
    if (t < 64) {
      const int nt = t >> 4, c16 = t & 15;
      float s = pr[(0 + nt) * 16 + c16] + pr[(4 + nt) * 16 + c16] +
                pr[(8 + nt) * 16 + c16] + pr[(12 + nt) * 16 + c16];
      atomicAdd(&pooled_sum[b * 64 + t], s);
    }
  } else {
    // ------------------------- tree branch -------------------------
    const int e = lane;
    for (int i = t; i < 4096; i += 256) {
      ((float*)sm.tr.W3[0])[i] = Wk[i];
      ((float*)sm.tr.W3[1])[i] = Wq[i];
      ((float*)sm.tr.W3[2])[i] = Wv[i];
    }
    __syncthreads();

    const int tree = (blockIdx.x - 512) * 4 + wid;   // 0..63
    const int b = tree >> 3;
    const int* tid = table_ids + tree * 17;
    const int* lid = l_ids + tree * 32;
    const int* rid = r_ids + tree * 32;

    float prev = rel_table[tid[0] * 64 + e];

    for (int d = 0; d < 16; ++d) {
      const int l0 = lid[d * 2], l1 = lid[d * 2 + 1];
      const int r0 = rid[d * 2], r1 = rid[d * 2 + 1];
      const float lce = 0.5f * (col_table[l0 * 64 + e] + col_table[l1 * 64 + e]);
      const float rce = 0.5f * (col_table[r0 * 64 + e] + col_table[r1 * 64 + e]);
      const float rte = rel_table[tid[1 + d] * 64 + e];
      float4 qv0; qv0.x = prev; qv0.y = lce; qv0.z = rce; qv0.w = rte;
      *(float4*)&sm.tr.qT[wid][e][0] = qv0;
      __syncthreads();

      float K[4] = {0, 0, 0, 0}, Q[4] = {0, 0, 0, 0}, V[4] = {0, 0, 0, 0};
#pragma unroll 8
      for (int i = 0; i < 64; ++i) {
        const f32x4 qv = *(const f32x4*)&sm.tr.qT[wid][i][0];
        const float wk = sm.tr.W3[0][i][e];
        const float wq = sm.tr.W3[1][i][e];
        const float wvv = sm.tr.W3[2][i][e];
#pragma unroll
        for (int j = 0; j < 4; ++j) {
          K[j] += qv[j] * wk;
          Q[j] += qv[j] * wq;
          V[j] += qv[j] * wvv;
        }
      }

      float sc[4][4];
#pragma unroll
      for (int j = 0; j < 4; ++j)
#pragma unroll
        for (int k = 0; k < 4; ++k) {
          float p = Q[j] * K[k];
          p += __shfl_xor(p, 1);  p += __shfl_xor(p, 2);  p += __shfl_xor(p, 4);
          p += __shfl_xor(p, 8);  p += __shfl_xor(p, 16); p += __shfl_xor(p, 32);
          sc[j][k] = p * (1.f / 64.f);
        }

      float wsum[4] = {0, 0, 0, 0};
#pragma unroll
      for (int j = 0; j < 4; ++j) {
        float mx = fmaxf(fmaxf(sc[j][0], sc[j][1]), fmaxf(sc[j][2], sc[j][3]));
        float a0 = __expf(sc[j][0] - mx), a1 = __expf(sc[j][1] - mx);
        float a2 = __expf(sc[j][2] - mx), a3 = __expf(sc[j][3] - mx);
        float inv = 1.f / (a0 + a1 + a2 + a3);
        wsum[0] += a0 * inv; wsum[1] += a1 * inv; wsum[2] += a2 * inv; wsum[3] += a3 * inv;
      }

      prev = wsum[0] * V[0] + wsum[1] * V[1] + wsum[2] * V[2] + wsum[3] * V[3];
      __syncthreads();
    }
    atomicAdd(&tree_emb[b * 64 + e], prev);
  }
}

// ---------------------------------------------------------------------------
// Kernel 2: logits = [pooled_sum/4096 || tree_emb] @ fc_w  + clip(log(mask))
// grid 128 x 256
// ---------------------------------------------------------------------------
__global__ void k_final(const float* __restrict__ action_mask, const float* __restrict__ fc_w,
                        const float* __restrict__ pooled_sum, const float* __restrict__ tree_emb,
                        float* __restrict__ out) {
  __shared__ float c[128];
  const int b = blockIdx.x >> 4;
  const int a = ((blockIdx.x & 15) << 8) + threadIdx.x;
  if (threadIdx.x < 128) {
    c[threadIdx.x] = (threadIdx.x < 64) ? pooled_sum[b * 64 + threadIdx.x] * (1.f / 4096.f)
                                        : tree_emb[b * 64 + threadIdx.x - 64];
  }
  __syncthreads();
  float acc = 0.f;
  for (int i = 0; i < 128; ++i) acc += c[i] * fc_w[i * 4096 + a];
  const float m = action_mask[b * 4096 + a];
  float lg = __logf(m);
  lg = fminf(fmaxf(lg, -3.4e38f), 3.4e38f);
  out[b * 4096 + a] = lg + acc;
}

// ---------------------------------------------------------------------------
extern "C" void kernel_launch(void* const* d_in, const int* in_sizes, int n_in,
                              void* d_out, int out_size, void* d_ws, size_t ws_size,
                              hipStream_t stream) {
  const float* link = (const float*)d_in[0];
  const float* mask = (const float*)d_in[1];
  const float* col = (const float*)d_in[2];
  const float* rel = (const float*)d_in[3];
  const float* GW = (const float*)d_in[4];
  const float* gb = (const float*)d_in[5];
  const float* Wk = (const float*)d_in[6];
  const float* Wq = (const float*)d_in[7];
  const float* Wv = (const float*)d_in[8];
  const float* fcw = (const float*)d_in[9];
  const int* tids = (const int*)d_in[10];
  const int* lids = (const int*)d_in[11];
  const int* rids = (const int*)d_in[12];
  float* out = (float*)d_out;

  unsigned short* bT = (unsigned short*)d_ws;               // 512 KB  (relGW^T bf16)
  float* accums = (float*)((char*)d_ws + 512 * 1024);       // 1024 floats
  float* pooled_sum = accums;                               // [8][64]
  float* tree = accums + 512;                               // [8][64]

  hipLaunchKernelGGL(k_prep, dim3(64), dim3(256), 0, stream, rel, GW, bT, accums);
  hipLaunchKernelGGL(k_main, dim3(528), dim3(256), 0, stream,
                     link, bT, gb, pooled_sum,
                     col, rel, Wk, Wq, Wv, tids, lids, rids, tree);
  hipLaunchKernelGGL(k_final, dim3(128), dim3(256), 0, stream, mask, fcw, pooled_sum, tree, out);
}

// Round 8
// 167.053 us; speedup vs baseline: 1.2362x; 1.2026x over previous
//
#include <hip/hip_runtime.h>
#include <hip/hip_bf16.h>
#include <stdint.h>

typedef __attribute__((ext_vector_type(8))) short short8;
typedef __attribute__((ext_vector_type(4))) float f32x4;

union FragU { short8 s; __hip_bfloat162 h[4]; };

__device__ __forceinline__ unsigned short f2bf(float f) {
  union { float f; unsigned int u; } v; v.f = f;
  unsigned int r = v.u + 0x7fffu + ((v.u >> 16) & 1u);
  return (unsigned short)(r >> 16);
}

// async global -> LDS, 16B per lane. LDS dest = uniform base + lane*16 (linear).
#define GLOAD_LDS16(gp, lp) \
  __builtin_amdgcn_global_load_lds((const __attribute__((address_space(1))) void*)(gp), \
                                   (__attribute__((address_space(3))) void*)(lp), 16, 0, 0)

// ---------------------------------------------------------------------------
// Kernel 0: bT[e][k] = bf16( (rel @ GW)[k][e] )   (64 x 4096); zero accums.
// grid 64 x 256
// ---------------------------------------------------------------------------
__global__ void k_prep(const float* __restrict__ rel, const float* __restrict__ GW,
                       unsigned short* __restrict__ bT, float* __restrict__ accums) {
  __shared__ float tile[64][65];   // rel rows j*64..+64  [k][i]
  __shared__ float gws[64][64];    // GW [i][e]
  const int j = blockIdx.x;
  const int t = threadIdx.x;
#pragma unroll
  for (int p = 0; p < 16; ++p) {
    int elem = p * 256 + t;
    int kk = elem >> 6, ee = elem & 63;
    tile[kk][ee] = rel[(j * 64 + kk) * 64 + ee];
    ((float*)gws)[elem] = GW[elem];
  }
  __syncthreads();
  const int e = t >> 2, chunk = t & 3;
  union { unsigned short u16[16]; uint4 v[2]; } tmp;
  for (int i = 0; i < 16; ++i) {
    float acc = 0.f;
#pragma unroll
    for (int ii = 0; ii < 64; ++ii) acc += tile[chunk * 16 + i][ii] * gws[ii][e];
    tmp.u16[i] = f2bf(acc);
  }
  unsigned short* dst = bT + e * 4096 + j * 64 + chunk * 16;
  *(uint4*)(dst) = tmp.v[0];
  *(uint4*)(dst + 8) = tmp.v[1];
  if (j == 0) {
    accums[t] = 0.f; accums[t + 256] = 0.f; accums[t + 512] = 0.f; accums[t + 768] = 0.f;
  }
}

// ---------------------------------------------------------------------------
// Fused main kernel.
//   blocks 0..511   : GEMM  C = link[b][64 rows] @ relGW  (K=4096, cols=64)
//     2-phase double-buffered 64x64 tiles via global_load_lds, ONE
//     drain+barrier per tile.  NEW: per-block k-phase rotation so the 512
//     blocks cover all 64 tile-phases at any instant (kills the L2-slice /
//     HBM-channel aliasing of synchronized 256B strips at 16KB stride).
//   blocks 512..527 : tree attention (4 trees per block, one per wave)
// ---------------------------------------------------------------------------
__global__ __launch_bounds__(256, 3) void k_main(
    const float* __restrict__ link, const unsigned short* __restrict__ bT,
    const float* __restrict__ gbias, float* __restrict__ pooled_sum,
    const float* __restrict__ col_table, const float* __restrict__ rel_table,
    const float* __restrict__ Wk, const float* __restrict__ Wq, const float* __restrict__ Wv,
    const int* __restrict__ table_ids, const int* __restrict__ l_ids,
    const int* __restrict__ r_ids, float* __restrict__ tree_emb) {
  __shared__ union {
    struct { char a[2][64 * 256]; char b[2][64 * 128]; } g;    // 48 KB
    struct { float W3[3][64][64]; float qT[4][64][4]; } tr;    // 52 KB
  } sm;

  const int t = threadIdx.x;
  const int lane = t & 63;
  const int wid = t >> 6;

  if (blockIdx.x < 512) {
    // ------------------------ GEMM branch ------------------------
    const int b = blockIdx.x >> 6;
    const int rb = blockIdx.x & 63;
    const int rowBase = rb * 64;
    const int phase = (rb + b * 8) & 63;        // k-phase decorrelation
    const int wrow = wid * 16;
    const int g = lane >> 4;          // k-group 0..3
    const int r = lane & 15;          // row/col within fragment
    const uint32_t fr = (uint32_t)((r & 7) << 4);

    const char* linkb = (const char*)(link + ((size_t)b << 24));
    // A stage: 4 instrs/wave, each 1KB = 4 rows x 256B.
    const int a_ri = lane >> 4;                    // row within instr
    const uint32_t a_cb = (uint32_t)((lane & 15) * 16);
    // B stage: 2 instrs/wave, each 1KB = 8 e-rows x 128B.
    const int b_ei = lane >> 3;                    // e within instr (0..7)
    const uint32_t b_cb = (uint32_t)(((lane & 7) * 16) ^ ((uint32_t)(lane >> 3) << 4));

    f32x4 acc[4];
#pragma unroll
    for (int nt = 0; nt < 4; ++nt) acc[nt] = (f32x4){0.f, 0.f, 0.f, 0.f};

#define STAGE(buf, tt) do {                                                     \
    const size_t ka = (size_t)(tt) * 256;  /* 64k * 4B */                       \
    _Pragma("unroll")                                                           \
    for (int j = 0; j < 4; ++j) {                                               \
      const int row = wrow + 4 * j + a_ri;                                      \
      const uint32_t cb = a_cb ^ ((uint32_t)(row & 7) << 4);                    \
      GLOAD_LDS16(linkb + (size_t)(rowBase + row) * 16384 + ka + cb,            \
                  sm.g.a[buf] + (wrow + 4 * j) * 256);                          \
    }                                                                           \
    const size_t kb = (size_t)(tt) * 128;  /* 64k * 2B */                       \
    _Pragma("unroll")                                                           \
    for (int j = 0; j < 2; ++j) {                                               \
      const int e = wrow + 8 * j + b_ei;                                        \
      GLOAD_LDS16((const char*)bT + (size_t)e * 8192 + kb + b_cb,               \
                  sm.g.b[buf] + (wrow + 8 * j) * 128);                          \
    }                                                                           \
  } while (0)

#define COMPUTE(buf) do {                                                       \
    const char* ab = sm.g.a[buf] + (wrow + r) * 256;                            \
    const char* bb = sm.g.b[buf];                                               \
    _Pragma("unroll")                                                           \
    for (int kc = 0; kc < 2; ++kc) {                                            \
      const uint32_t o0 = ((uint32_t)(kc * 128 + g * 32)) ^ fr;                 \
      const f32x4 a0 = *(const f32x4*)(ab + o0);                                \
      const f32x4 a1 = *(const f32x4*)(ab + (o0 ^ 16));                         \
      FragU f;                                                                  \
      f.h[0] = __float22bfloat162_rn(float2{a0[0], a0[1]});                     \
      f.h[1] = __float22bfloat162_rn(float2{a0[2], a0[3]});                     \
      f.h[2] = __float22bfloat162_rn(float2{a1[0], a1[1]});                     \
      f.h[3] = __float22bfloat162_rn(float2{a1[2], a1[3]});                     \
      const uint32_t ob = ((uint32_t)(kc * 64 + g * 16)) ^ fr;                  \
      _Pragma("unroll")                                                         \
      for (int nt = 0; nt < 4; ++nt) {                                          \
        const short8 bf = *(const short8*)(bb + (nt * 16 + r) * 128 + ob);      \
        acc[nt] = __builtin_amdgcn_mfma_f32_16x16x32_bf16(f.s, bf, acc[nt], 0, 0, 0); \
      }                                                                         \
    }                                                                           \
  } while (0)

    STAGE(0, phase);
    __syncthreads();
    int cur = 0;
    for (int tti = 0; tti < 64; ++tti) {
      if (tti < 63) STAGE(cur ^ 1, (tti + 1 + phase) & 63);   // in flight during compute
      COMPUTE(cur);
      __syncthreads();                        // drains vmcnt; next buf ready
      cur ^= 1;
    }

    // ---- epilogue: relu(C + bias) colsum, all in registers ----
    float part[4];
#pragma unroll
    for (int nt = 0; nt < 4; ++nt) {
      const float gbv = gbias[nt * 16 + r];
      float s = 0.f;
#pragma unroll
      for (int j = 0; j < 4; ++j) s += fmaxf(acc[nt][j] + gbv, 0.f);
      s += __shfl_xor(s, 16);
      s += __shfl_xor(s, 32);
      part[nt] = s;
    }
    float* pr = (float*)sm.g.a[0];
    if (g == 0) {
#pragma unroll
      for (int nt = 0; nt < 4; ++nt) pr[(wid * 4 + nt) * 16 + r] = part[nt];
    }
    __syncthreads();
    if (t < 64) {
      const int nt = t >> 4, c16 = t & 15;
      float s = pr[(0 + nt) * 16 + c16] + pr[(4 + nt) * 16 + c16] +
                pr[(8 + nt) * 16 + c16] + pr[(12 + nt) * 16 + c16];
      atomicAdd(&pooled_sum[b * 64 + t], s);
    }
  } else {
    // ------------------------- tree branch -------------------------
    const int e = lane;
    for (int i = t; i < 4096; i += 256) {
      ((float*)sm.tr.W3[0])[i] = Wk[i];
      ((float*)sm.tr.W3[1])[i] = Wq[i];
      ((float*)sm.tr.W3[2])[i] = Wv[i];
    }
    __syncthreads();

    const int tree = (blockIdx.x - 512) * 4 + wid;   // 0..63
    const int b = tree >> 3;
    const int* tid = table_ids + tree * 17;
    const int* lid = l_ids + tree * 32;
    const int* rid = r_ids + tree * 32;

    float prev = rel_table[tid[0] * 64 + e];

    for (int d = 0; d < 16; ++d) {
      const int l0 = lid[d * 2], l1 = lid[d * 2 + 1];
      const int r0 = rid[d * 2], r1 = rid[d * 2 + 1];
      const float lce = 0.5f * (col_table[l0 * 64 + e] + col_table[l1 * 64 + e]);
      const float rce = 0.5f * (col_table[r0 * 64 + e] + col_table[r1 * 64 + e]);
      const float rte = rel_table[tid[1 + d] * 64 + e];
      float4 qv0; qv0.x = prev; qv0.y = lce; qv0.z = rce; qv0.w = rte;
      *(float4*)&sm.tr.qT[wid][e][0] = qv0;
      __syncthreads();

      float K[4] = {0, 0, 0, 0}, Q[4] = {0, 0, 0, 0}, V[4] = {0, 0, 0, 0};
#pragma unroll 8
      for (int i = 0; i < 64; ++i) {
        const f32x4 qv = *(const f32x4*)&sm.tr.qT[wid][i][0];
        const float wk = sm.tr.W3[0][i][e];
        const float wq = sm.tr.W3[1][i][e];
        const float wvv = sm.tr.W3[2][i][e];
#pragma unroll
        for (int j = 0; j < 4; ++j) {
          K[j] += qv[j] * wk;
          Q[j] += qv[j] * wq;
          V[j] += qv[j] * wvv;
        }
      }

      float sc[4][4];
#pragma unroll
      for (int j = 0; j < 4; ++j)
#pragma unroll
        for (int k = 0; k < 4; ++k) {
          float p = Q[j] * K[k];
          p += __shfl_xor(p, 1);  p += __shfl_xor(p, 2);  p += __shfl_xor(p, 4);
          p += __shfl_xor(p, 8);  p += __shfl_xor(p, 16); p += __shfl_xor(p, 32);
          sc[j][k] = p * (1.f / 64.f);
        }

      float wsum[4] = {0, 0, 0, 0};
#pragma unroll
      for (int j = 0; j < 4; ++j) {
        float mx = fmaxf(fmaxf(sc[j][0], sc[j][1]), fmaxf(sc[j][2], sc[j][3]));
        float a0 = __expf(sc[j][0] - mx), a1 = __expf(sc[j][1] - mx);
        float a2 = __expf(sc[j][2] - mx), a3 = __expf(sc[j][3] - mx);
        float inv = 1.f / (a0 + a1 + a2 + a3);
        wsum[0] += a0 * inv; wsum[1] += a1 * inv; wsum[2] += a2 * inv; wsum[3] += a3 * inv;
      }

      prev = wsum[0] * V[0] + wsum[1] * V[1] + wsum[2] * V[2] + wsum[3] * V[3];
      __syncthreads();
    }
    atomicAdd(&tree_emb[b * 64 + e], prev);
  }
}

// ---------------------------------------------------------------------------
// Kernel 2: logits = [pooled_sum/4096 || tree_emb] @ fc_w  + clip(log(mask))
// grid 128 x 256
// ---------------------------------------------------------------------------
__global__ void k_final(const float* __restrict__ action_mask, const float* __restrict__ fc_w,
                        const float* __restrict__ pooled_sum, const float* __restrict__ tree_emb,
                        float* __restrict__ out) {
  __shared__ float c[128];
  const int b = blockIdx.x >> 4;
  const int a = ((blockIdx.x & 15) << 8) + threadIdx.x;
  if (threadIdx.x < 128) {
    c[threadIdx.x] = (threadIdx.x < 64) ? pooled_sum[b * 64 + threadIdx.x] * (1.f / 4096.f)
                                        : tree_emb[b * 64 + threadIdx.x - 64];
  }
  __syncthreads();
  float acc = 0.f;
  for (int i = 0; i < 128; ++i) acc += c[i] * fc_w[i * 4096 + a];
  const float m = action_mask[b * 4096 + a];
  float lg = __logf(m);
  lg = fminf(fmaxf(lg, -3.4e38f), 3.4e38f);
  out[b * 4096 + a] = lg + acc;
}

// ---------------------------------------------------------------------------
extern "C" void kernel_launch(void* const* d_in, const int* in_sizes, int n_in,
                              void* d_out, int out_size, void* d_ws, size_t ws_size,
                              hipStream_t stream) {
  const float* link = (const float*)d_in[0];
  const float* mask = (const float*)d_in[1];
  const float* col = (const float*)d_in[2];
  const float* rel = (const float*)d_in[3];
  const float* GW = (const float*)d_in[4];
  const float* gb = (const float*)d_in[5];
  const float* Wk = (const float*)d_in[6];
  const float* Wq = (const float*)d_in[7];
  const float* Wv = (const float*)d_in[8];
  const float* fcw = (const float*)d_in[9];
  const int* tids = (const int*)d_in[10];
  const int* lids = (const int*)d_in[11];
  const int* rids = (const int*)d_in[12];
  float* out = (float*)d_out;

  unsigned short* bT = (unsigned short*)d_ws;               // 512 KB  (relGW^T bf16)
  float* accums = (float*)((char*)d_ws + 512 * 1024);       // 1024 floats
  float* pooled_sum = accums;                               // [8][64]
  float* tree = accums + 512;                               // [8][64]

  hipLaunchKernelGGL(k_prep, dim3(64), dim3(256), 0, stream, rel, GW, bT, accums);
  hipLaunchKernelGGL(k_main, dim3(528), dim3(256), 0, stream,
                     link, bT, gb, pooled_sum,
                     col, rel, Wk, Wq, Wv, tids, lids, rids, tree);
  hipLaunchKernelGGL(k_final, dim3(128), dim3(256), 0, stream, mask, fcw, pooled_sum, tree, out);
}